// Round 13
// baseline (1624.124 us; speedup 1.0000x reference)
//
#include <hip/hip_runtime.h>

#define B_ 256
#define S_ 64
#define I_ 256
#define H_ 1024
#define NODE_ 4
#define NB 256
#define NG 8     // row groups (32 batch rows each) -- data-decoupled, own barrier
#define GSZ 32   // blocks per group (one 32-col strip each)

typedef __attribute__((ext_vector_type(8))) short short8;
typedef __attribute__((ext_vector_type(4))) float f32x4;

// fp32 -> bf16 round-to-nearest-even on raw bits
__device__ __forceinline__ short f2bf(float f) {
    unsigned u = __float_as_uint(f);
    u += 0x7fffu + ((u >> 16) & 1u);
    return (short)(u >> 16);
}
__device__ __forceinline__ unsigned pack2(float a, float b) {
    return (unsigned)(unsigned short)f2bf(a) | ((unsigned)(unsigned short)f2bf(b) << 16);
}

// fast tanh: |err| ~1e-7 rel, negligible vs bf16 h quantization
__device__ __forceinline__ float ftanh(float x) {
    float e = __expf(2.0f * fabsf(x));
    float r = __builtin_fmaf(-2.0f, __builtin_amdgcn_rcpf(e + 1.0f), 1.0f);
    return copysignf(r, x);
}

// Verified round-6 barrier: agent-scope counter at LLC (used once, startup).
__device__ __forceinline__ void gbar_slow(unsigned* cnt, unsigned target) {
    __syncthreads();
    if (threadIdx.x == 0) {
        __hip_atomic_fetch_add(cnt, 1u, __ATOMIC_RELAXED, __HIP_MEMORY_SCOPE_AGENT);
        while (__hip_atomic_load(cnt, __ATOMIC_RELAXED, __HIP_MEMORY_SCOPE_AGENT) < target)
            __builtin_amdgcn_s_sleep(1);
    }
    __syncthreads();
}

__global__ __launch_bounds__(256, 1)
void odernn_persist(const float* __restrict__ x, const float* __restrict__ t,
                    const float* __restrict__ W_in, const float* __restrict__ b_in,
                    const float* __restrict__ W_h, const float* __restrict__ b_h,
                    const float* __restrict__ W_ode, const float* __restrict__ b_ode,
                    float* __restrict__ out,
                    unsigned short* __restrict__ h0buf, unsigned short* __restrict__ h1buf,
                    unsigned short* __restrict__ Whbf, unsigned short* __restrict__ Winbf,
                    unsigned* __restrict__ cnts)
{
    __shared__ short Wlds[32 * 1024];   // 64 KB: bf16 W_ode col-slice, XOR-swizzled
    __shared__ short Hlds[32 * 1024];   // 64 KB: staged h strip / publish gather

    const int tid = threadIdx.x;
    const int blk = blockIdx.x;
    const int bi = blk & 7;           // row group (32 batch rows)
    const int bj = blk >> 3;          // 0..31 col strip
    const int lane = tid & 63;
    const int wv = tid >> 6;
    const int wr = wv >> 1, wc = wv & 1;
    const int r16 = lane & 15, kg = lane >> 4;

    // ---- prologue A: convert W_h, W_in to bf16 in ws (disjoint chunks) ----
    {
        const int g = blk * 256 + tid;              // 0..65535
        const float* src = W_h + (size_t)g * 16;    // 16 floats each
        unsigned* dst = (unsigned*)Whbf + (size_t)g * 8;
#pragma unroll
        for (int i = 0; i < 4; ++i) {
            float4 v = *(const float4*)(src + i * 4);
            __hip_atomic_store(dst + i * 2,     pack2(v.x, v.y), __ATOMIC_RELAXED, __HIP_MEMORY_SCOPE_AGENT);
            __hip_atomic_store(dst + i * 2 + 1, pack2(v.z, v.w), __ATOMIC_RELAXED, __HIP_MEMORY_SCOPE_AGENT);
        }
        float4 v = *(const float4*)(W_in + (size_t)g * 4);
        unsigned* d2 = (unsigned*)Winbf + (size_t)g * 2;
        __hip_atomic_store(d2,     pack2(v.x, v.y), __ATOMIC_RELAXED, __HIP_MEMORY_SCOPE_AGENT);
        __hip_atomic_store(d2 + 1, pack2(v.z, v.w), __ATOMIC_RELAXED, __HIP_MEMORY_SCOPE_AGENT);
    }

    // ---- prologue B: stage W_ode[bj*32 .. +32][:] as bf16 into LDS ----
    {
        const int c = tid >> 3;
        const int ks = (tid & 7) * 128;
        const float* wsrc = W_ode + (size_t)(bj * 32 + c) * H_ + ks;
        for (int i = 0; i < 16; ++i) {
            float4 v0 = *(const float4*)(wsrc + i * 8);
            float4 v1 = *(const float4*)(wsrc + i * 8 + 4);
            short8 sv = { f2bf(v0.x), f2bf(v0.y), f2bf(v0.z), f2bf(v0.w),
                          f2bf(v1.x), f2bf(v1.y), f2bf(v1.z), f2bf(v1.w) };
            int idx = c * 1024 + ks + i * 8;
            *(short8*)&Wlds[idx ^ ((c & 7) << 3)] = sv;
        }
    }

    const int rowb = bi * 32 + wr * 16 + kg * 4;   // first of 4 output rows
    const int arow = bi * 32 + wr * 16 + r16;      // A-fragment row (batch)
    const int col  = bj * 32 + wc * 16 + r16;      // output column
    const int wb   = wc * 16 + r16;                // W-slice row for B-fragment

    const int hrow = wr * 16 + r16;                // A row within the 32-row strip
    const char* aBase = (const char*)Hlds + hrow * 2048;
    const int hswz = (hrow & 7) << 4;              // byte XOR for Hlds reads

    const float bodec = b_ode[col];
    const float binc  = b_in[col] + b_h[col];

    f32x4 hreg = {0.f, 0.f, 0.f, 0.f};
    // publish h0 = 0 (agent -> LLC, own tile)
#pragma unroll
    for (int r = 0; r < 4; ++r)
        __hip_atomic_store(&h0buf[(size_t)(rowb + r) * H_ + col], (unsigned short)0,
                           __ATOMIC_RELAXED, __HIP_MEMORY_SCOPE_AGENT);

    // one GLOBAL barrier (verified): conversions + h0 zeros visible everywhere
    gbar_slow(&cnts[512], NB);

    unsigned* flags = cnts + 1024 + bi * 32;   // 32 flag words = one 128B line per group
    unsigned ep = 1;

    // Stage helpers: K-split halves. Per thread: row = tid>>3, 8B cluster
    // (tid&7); half h covers bytes h*1024 .. +1023 of the row (j*64B chunks).
    const int srow = tid >> 3, scl = tid & 7;
    const int swz_w = (srow & 7) << 4;   // write-side swizzle, same formula as reads

    auto stage_issue_half = [&](const unsigned short* hsrc, int half, unsigned long long* v) {
        const unsigned long long* src =
            (const unsigned long long*)(hsrc + (size_t)bi * 32 * H_) +
            srow * 256 + half * 128 + scl;
#pragma unroll
        for (int j = 0; j < 16; ++j)
            v[j] = __hip_atomic_load(src + j * 8, __ATOMIC_RELAXED, __HIP_MEMORY_SCOPE_AGENT);
    };
    auto stage_write_half = [&](int half, const unsigned long long* v) {
#pragma unroll
        for (int j = 0; j < 16; ++j) {
            int inb = half * 1024 + j * 64 + scl * 8;
            *(unsigned long long*)((char*)Hlds + srow * 2048 + (inb ^ swz_w)) = v[j];
        }
    };

    // MFMA over one K half (512) from Hlds (Euler: B from Wlds)
    auto mfma_half_lds = [&](int base, f32x4& acc0, f32x4& acc1) {
#pragma unroll
        for (int k0 = base; k0 < base + 512; k0 += 64) {
            short8 a0 = *(const short8*)(aBase + (((k0 + kg * 8) * 2) ^ hswz));
            short8 b0 = *(const short8*)&Wlds[(wb * 1024 + k0 + kg * 8) ^ ((wb & 7) << 3)];
            acc0 = __builtin_amdgcn_mfma_f32_16x16x32_bf16(a0, b0, acc0, 0, 0, 0);
            short8 a1 = *(const short8*)(aBase + (((k0 + 32 + kg * 8) * 2) ^ hswz));
            short8 b1 = *(const short8*)&Wlds[(wb * 1024 + k0 + 32 + kg * 8) ^ ((wb & 7) << 3)];
            acc1 = __builtin_amdgcn_mfma_f32_16x16x32_bf16(a1, b1, acc1, 0, 0, 0);
        }
    };
    // MFMA over one K half from Hlds with B from global bf16 (update: W_h)
    auto mfma_half_glb = [&](int base, const unsigned short* whB, f32x4& acc0, f32x4& acc1) {
#pragma unroll
        for (int k0 = base; k0 < base + 512; k0 += 64) {
            short8 a0 = *(const short8*)(aBase + (((k0 + kg * 8) * 2) ^ hswz));
            short8 b0 = *(const short8*)(whB + k0);
            acc0 = __builtin_amdgcn_mfma_f32_16x16x32_bf16(a0, b0, acc0, 0, 0, 0);
            short8 a1 = *(const short8*)(aBase + (((k0 + 32 + kg * 8) * 2) ^ hswz));
            short8 b1 = *(const short8*)(whB + k0 + 32);
            acc1 = __builtin_amdgcn_mfma_f32_16x16x32_bf16(a1, b1, acc1, 0, 0, 0);
        }
    };

    // Publish this block's 32x32 bf16 tile + flag-vector group barrier.
    // Gather in LDS; wave0 does 256 coalesced u64 agent stores, drains its
    // vmcnt, lane0 agent-stores the epoch flag, wave0 polls all 32 flags
    // (one line-coalesced load + __all). All agent scope: staleness-free.
    auto publish_barrier = [&](unsigned short* dst, f32x4 pv, unsigned epoch) {
        __syncthreads();                    // all waves done reading Hlds (MFMA)
        short* Hp = (short*)Hlds;
#pragma unroll
        for (int r = 0; r < 4; ++r)
            Hp[(wr * 16 + kg * 4 + r) * 32 + wc * 16 + r16] = f2bf(pv[r]);
        __syncthreads();                    // Hp tile complete
        if (wv == 0) {
#pragma unroll
            for (int j = 0; j < 4; ++j) {
                int idx = j * 64 + lane;
                int row = idx >> 3, cg = idx & 7;
                unsigned long long vv = *(unsigned long long*)&Hp[row * 32 + cg * 4];
                __hip_atomic_store(
                    (unsigned long long*)&dst[(size_t)(bi * 32 + row) * H_ + bj * 32 + cg * 4],
                    vv, __ATOMIC_RELAXED, __HIP_MEMORY_SCOPE_AGENT);
            }
            asm volatile("s_waitcnt vmcnt(0)" ::: "memory");   // h stores at LLC
            if (lane == 0)
                __hip_atomic_store(&flags[bj], epoch, __ATOMIC_RELAXED, __HIP_MEMORY_SCOPE_AGENT);
            const unsigned* fp = flags + (lane & 31);
            for (;;) {
                unsigned v = __hip_atomic_load(fp, __ATOMIC_RELAXED, __HIP_MEMORY_SCOPE_AGENT);
                if (__all((int)(v >= epoch))) break;
                __builtin_amdgcn_s_sleep(1);
            }
        }
        __syncthreads();                    // release: hout complete for the group
    };

    const unsigned short* hin = h0buf;
    unsigned short* hout = h1buf;

    for (int s = 0; s < S_; ++s) {
        if (s > 0) {
            const float dth = (t[s] - t[s - 1]) * 0.25f;
            for (int e = 0; e < NODE_; ++e) {
                unsigned long long vA[16], vB[16];
                stage_issue_half(hin, 0, vA);      // K 0..511 loads
                stage_write_half(0, vA);           // (compiler waits A)
                stage_issue_half(hin, 1, vB);      // K 512..1023 in flight
                __syncthreads();
                f32x4 acc0 = {0.f, 0.f, 0.f, 0.f}, acc1 = {0.f, 0.f, 0.f, 0.f};
                mfma_half_lds(0, acc0, acc1);      // overlaps half-B latency
                stage_write_half(1, vB);           // (compiler waits B)
                __syncthreads();
                mfma_half_lds(512, acc0, acc1);
                f32x4 acc = acc0 + acc1;
#pragma unroll
                for (int r = 0; r < 4; ++r)
                    hreg[r] += dth * ftanh(acc[r] + bodec);
                publish_barrier(hout, hreg, ep); ++ep;
                const unsigned short* tmp = hin; hin = hout; hout = (unsigned short*)tmp;
            }
        }
        // ---- update: h = tanh(x_s @ W_in^T + h @ W_h^T + b_in + b_h) ----
        {
            const unsigned short* whB = Whbf + (size_t)col * H_ + kg * 8;
            unsigned long long vA[16], vB[16];
            stage_issue_half(hin, 0, vA);
            stage_write_half(0, vA);
            stage_issue_half(hin, 1, vB);
            __syncthreads();
            f32x4 acc0 = {0.f, 0.f, 0.f, 0.f}, acc1 = {0.f, 0.f, 0.f, 0.f};
            mfma_half_glb(0, whB, acc0, acc1);
            stage_write_half(1, vB);
            __syncthreads();
            mfma_half_glb(512, whB, acc0, acc1);

            const float* xB = x + ((size_t)arow * S_ + s) * I_ + kg * 8;
            const unsigned short* wiB = Winbf + (size_t)col * I_ + kg * 8;
#pragma unroll
            for (int k2 = 0; k2 < I_; k2 += 64) {
                float4 a0f = *(const float4*)(xB + k2);
                float4 a1f = *(const float4*)(xB + k2 + 4);
                short8 a = { f2bf(a0f.x), f2bf(a0f.y), f2bf(a0f.z), f2bf(a0f.w),
                             f2bf(a1f.x), f2bf(a1f.y), f2bf(a1f.z), f2bf(a1f.w) };
                short8 b = *(const short8*)(wiB + k2);
                acc0 = __builtin_amdgcn_mfma_f32_16x16x32_bf16(a, b, acc0, 0, 0, 0);
                // K-window k2+32..k2+63: A must come from xB + k2 + 32 (bug was +8/+12)
                float4 a2f = *(const float4*)(xB + k2 + 32);
                float4 a3f = *(const float4*)(xB + k2 + 36);
                short8 a2 = { f2bf(a2f.x), f2bf(a2f.y), f2bf(a2f.z), f2bf(a2f.w),
                              f2bf(a3f.x), f2bf(a3f.y), f2bf(a3f.z), f2bf(a3f.w) };
                short8 b2 = *(const short8*)(wiB + k2 + 32);
                acc1 = __builtin_amdgcn_mfma_f32_16x16x32_bf16(a2, b2, acc1, 0, 0, 0);
            }
            f32x4 acc = acc0 + acc1;
            const bool last = (s == S_ - 1);
            f32x4 hv;
#pragma unroll
            for (int r = 0; r < 4; ++r) {
                hv[r] = ftanh(acc[r] + binc);
                hreg[r] = hv[r];
            }
            if (last) {
#pragma unroll
                for (int r = 0; r < 4; ++r)
                    out[(size_t)(rowb + r) * H_ + col] = hv[r];
            } else {
                publish_barrier(hout, hv, ep); ++ep;
                const unsigned short* tmp = hin; hin = hout; hout = (unsigned short*)tmp;
            }
        }
    }
}

extern "C" void kernel_launch(void* const* d_in, const int* in_sizes, int n_in,
                              void* d_out, int out_size, void* d_ws, size_t ws_size,
                              hipStream_t stream) {
    const float* x     = (const float*)d_in[0];
    const float* t     = (const float*)d_in[1];
    const float* W_in  = (const float*)d_in[2];
    const float* b_in  = (const float*)d_in[3];
    const float* W_h   = (const float*)d_in[4];
    const float* b_h   = (const float*)d_in[5];
    const float* W_ode = (const float*)d_in[6];
    const float* b_ode = (const float*)d_in[7];

    unsigned short* h0    = (unsigned short*)d_ws;
    unsigned short* h1    = h0 + (size_t)B_ * H_;
    unsigned short* Whbf  = h1 + (size_t)B_ * H_;
    unsigned short* Winbf = Whbf + (size_t)H_ * H_;
    unsigned* cnts = (unsigned*)(Winbf + (size_t)H_ * I_);
    // layout (uints): [512]=global counter; [1024 + bi*32 + bj] = epoch flags
    // (one 128B line per group)

    (void)hipMemsetAsync(cnts, 0, (1024 + NG * GSZ) * sizeof(unsigned), stream);

    odernn_persist<<<dim3(NB), dim3(256), 0, stream>>>(
        x, t, W_in, b_in, W_h, b_h, W_ode, b_ode,
        (float*)d_out, h0, h1, Whbf, Winbf, cnts);
}

// Round 14
// 1283.222 us; speedup vs baseline: 1.2657x; 1.2657x over previous
//
#include <hip/hip_runtime.h>

#define B_ 256
#define S_ 64
#define I_ 256
#define H_ 1024
#define NODE_ 4
#define NB 256
#define NG 16    // row groups (16 batch rows each) -- data-decoupled, own barrier
#define GSZ 16   // blocks per group (one 64-col strip each)

typedef __attribute__((ext_vector_type(8))) short short8;
typedef __attribute__((ext_vector_type(4))) float f32x4;

// fp32 -> bf16 round-to-nearest-even on raw bits
__device__ __forceinline__ short f2bf(float f) {
    unsigned u = __float_as_uint(f);
    u += 0x7fffu + ((u >> 16) & 1u);
    return (short)(u >> 16);
}
__device__ __forceinline__ unsigned pack2(float a, float b) {
    return (unsigned)(unsigned short)f2bf(a) | ((unsigned)(unsigned short)f2bf(b) << 16);
}

// fast tanh: |err| ~1e-7 rel, negligible vs bf16 h quantization
__device__ __forceinline__ float ftanh(float x) {
    float e = __expf(2.0f * fabsf(x));
    float r = __builtin_fmaf(-2.0f, __builtin_amdgcn_rcpf(e + 1.0f), 1.0f);
    return copysignf(r, x);
}

// Verified round-6 barrier: agent-scope counter at LLC (used once, startup).
__device__ __forceinline__ void gbar_slow(unsigned* cnt, unsigned target) {
    __syncthreads();
    if (threadIdx.x == 0) {
        __hip_atomic_fetch_add(cnt, 1u, __ATOMIC_RELAXED, __HIP_MEMORY_SCOPE_AGENT);
        while (__hip_atomic_load(cnt, __ATOMIC_RELAXED, __HIP_MEMORY_SCOPE_AGENT) < target)
            __builtin_amdgcn_s_sleep(1);
    }
    __syncthreads();
}

__global__ __launch_bounds__(256, 1)
void odernn_persist(const float* __restrict__ x, const float* __restrict__ t,
                    const float* __restrict__ W_in, const float* __restrict__ b_in,
                    const float* __restrict__ W_h, const float* __restrict__ b_h,
                    const float* __restrict__ W_ode, const float* __restrict__ b_ode,
                    float* __restrict__ out,
                    unsigned short* __restrict__ h0buf, unsigned short* __restrict__ h1buf,
                    unsigned short* __restrict__ Whbf, unsigned short* __restrict__ Winbf,
                    unsigned* __restrict__ cnts)
{
    __shared__ short Wlds[64 * 1024];   // 128 KB: bf16 W_ode 64-col slice, XOR-swizzled
    __shared__ short Hlds[16 * 1024];   //  32 KB: staged 16-row h strip, XOR-swizzled

    const int tid = threadIdx.x;
    const int blk = blockIdx.x;
    const int bi = blk & 15;          // row group (16 batch rows)
    const int bj = blk >> 4;          // 0..15 col strip (64 cols)
    const int lane = tid & 63;
    const int wv = tid >> 6;          // wave 0..3: owns cols wv*16..+16 of the strip
    const int r16 = lane & 15, kg = lane >> 4;

    // ---- prologue A: convert W_h, W_in to bf16 in ws (disjoint chunks) ----
    {
        const int g = blk * 256 + tid;              // 0..65535
        const float* src = W_h + (size_t)g * 16;    // 16 floats each
        unsigned* dst = (unsigned*)Whbf + (size_t)g * 8;
#pragma unroll
        for (int i = 0; i < 4; ++i) {
            float4 v = *(const float4*)(src + i * 4);
            __hip_atomic_store(dst + i * 2,     pack2(v.x, v.y), __ATOMIC_RELAXED, __HIP_MEMORY_SCOPE_AGENT);
            __hip_atomic_store(dst + i * 2 + 1, pack2(v.z, v.w), __ATOMIC_RELAXED, __HIP_MEMORY_SCOPE_AGENT);
        }
        float4 v = *(const float4*)(W_in + (size_t)g * 4);
        unsigned* d2 = (unsigned*)Winbf + (size_t)g * 2;
        __hip_atomic_store(d2,     pack2(v.x, v.y), __ATOMIC_RELAXED, __HIP_MEMORY_SCOPE_AGENT);
        __hip_atomic_store(d2 + 1, pack2(v.z, v.w), __ATOMIC_RELAXED, __HIP_MEMORY_SCOPE_AGENT);
    }

    // ---- prologue B: stage W_ode[bj*64 .. +64][:] as bf16 into LDS ----
    {
        const int c = tid >> 2;              // 0..63 slice row
        const int ks = (tid & 3) * 256;      // 256-float k segment
        const float* wsrc = W_ode + (size_t)(bj * 64 + c) * H_ + ks;
        for (int i = 0; i < 32; ++i) {
            float4 v0 = *(const float4*)(wsrc + i * 8);
            float4 v1 = *(const float4*)(wsrc + i * 8 + 4);
            short8 sv = { f2bf(v0.x), f2bf(v0.y), f2bf(v0.z), f2bf(v0.w),
                          f2bf(v1.x), f2bf(v1.y), f2bf(v1.z), f2bf(v1.w) };
            int idx = c * 1024 + ks + i * 8;
            *(short8*)&Wlds[idx ^ ((c & 7) << 3)] = sv;
        }
    }

    const int row0  = bi * 16 + kg * 4;            // first of 4 output rows (global)
    const int arowg = bi * 16 + r16;               // x row for the A fragment (global)
    const int col   = bj * 64 + wv * 16 + r16;     // output column (global)
    const int wbrow = wv * 16 + r16;               // Wlds row for B fragment

    const char* aBase = (const char*)Hlds + r16 * 2048;
    const int hswz = (r16 & 7) << 4;               // byte XOR for Hlds reads

    const float bodec = b_ode[col];
    const float binc  = b_in[col] + b_h[col];

    f32x4 hreg = {0.f, 0.f, 0.f, 0.f};
    // publish h0 = 0 (agent -> LLC, own tile)
#pragma unroll
    for (int r = 0; r < 4; ++r)
        __hip_atomic_store(&h0buf[(size_t)(row0 + r) * H_ + col], (unsigned short)0,
                           __ATOMIC_RELAXED, __HIP_MEMORY_SCOPE_AGENT);

    // one GLOBAL barrier (verified): conversions + h0 zeros visible everywhere
    gbar_slow(&cnts[512], NB);

    unsigned* flags = cnts + 1024 + bi * 32;   // 16 flag words (own 128B line per group)
    unsigned ep = 1;

    // Stage this group's h strip (16 rows x 1024 bf16 = 32 KB) into Hlds.
    // r6-style: issue ALL 16 u64 agent loads, then write LDS (one latency
    // exposure), one sync. 16 threads/row, 16 u64 each.
    const int srow = tid >> 4, scl = tid & 15;
    const int swz_w = (srow & 7) << 4;
    auto stage = [&](const unsigned short* hsrc) {
        const unsigned long long* src =
            (const unsigned long long*)(hsrc + (size_t)bi * 16 * H_) + srow * 256 + scl;
        unsigned long long v[16];
#pragma unroll
        for (int j = 0; j < 16; ++j)
            v[j] = __hip_atomic_load(src + j * 16, __ATOMIC_RELAXED, __HIP_MEMORY_SCOPE_AGENT);
#pragma unroll
        for (int j = 0; j < 16; ++j) {
            int byte = (scl * 8 + j * 128) ^ swz_w;
            *(unsigned long long*)((char*)Hlds + srow * 2048 + byte) = v[j];
        }
        __syncthreads();
    };

    // Publish own 4 elems (16 contiguous bf16 per kg-row chunk -> 32B-chunk
    // semi-coalesced agent stores) + flag-vector group barrier (fan-in 16).
    auto publish_barrier = [&](unsigned short* dst, f32x4 pv, unsigned epoch) {
#pragma unroll
        for (int r = 0; r < 4; ++r)
            __hip_atomic_store(&dst[(size_t)(row0 + r) * H_ + col],
                               (unsigned short)f2bf(pv[r]),
                               __ATOMIC_RELAXED, __HIP_MEMORY_SCOPE_AGENT);
        __syncthreads();   // each wave drains its own stores (vmcnt0 before s_barrier)
        if (tid == 0)
            __hip_atomic_store(&flags[bj], epoch, __ATOMIC_RELAXED, __HIP_MEMORY_SCOPE_AGENT);
        if (wv == 0) {
            const unsigned* fp = flags + (lane & 15);
            for (;;) {
                unsigned v = __hip_atomic_load(fp, __ATOMIC_RELAXED, __HIP_MEMORY_SCOPE_AGENT);
                if (__all((int)(v >= epoch))) break;
                __builtin_amdgcn_s_sleep(1);
            }
        }
        __syncthreads();   // release: hout complete for the group
    };

    const unsigned short* hin = h0buf;
    unsigned short* hout = h1buf;

    for (int s = 0; s < S_; ++s) {
        if (s > 0) {
            const float dth = (t[s] - t[s - 1]) * 0.25f;
            for (int e = 0; e < NODE_; ++e) {
                stage(hin);
                f32x4 acc0 = {0.f, 0.f, 0.f, 0.f}, acc1 = {0.f, 0.f, 0.f, 0.f};
#pragma unroll
                for (int k0 = 0; k0 < H_; k0 += 64) {
                    short8 a0 = *(const short8*)(aBase + (((k0 + kg * 8) * 2) ^ hswz));
                    short8 b0 = *(const short8*)&Wlds[(wbrow * 1024 + k0 + kg * 8) ^ ((wbrow & 7) << 3)];
                    acc0 = __builtin_amdgcn_mfma_f32_16x16x32_bf16(a0, b0, acc0, 0, 0, 0);
                    short8 a1 = *(const short8*)(aBase + (((k0 + 32 + kg * 8) * 2) ^ hswz));
                    short8 b1 = *(const short8*)&Wlds[(wbrow * 1024 + k0 + 32 + kg * 8) ^ ((wbrow & 7) << 3)];
                    acc1 = __builtin_amdgcn_mfma_f32_16x16x32_bf16(a1, b1, acc1, 0, 0, 0);
                }
                f32x4 acc = acc0 + acc1;
#pragma unroll
                for (int r = 0; r < 4; ++r)
                    hreg[r] += dth * ftanh(acc[r] + bodec);
                publish_barrier(hout, hreg, ep); ++ep;
                const unsigned short* tmp = hin; hin = hout; hout = (unsigned short*)tmp;
            }
        }
        // ---- update: h = tanh(x_s @ W_in^T + h @ W_h^T + b_in + b_h) ----
        {
            stage(hin);
            const unsigned short* whB = Whbf + (size_t)col * H_ + kg * 8;
            f32x4 acc0 = {0.f, 0.f, 0.f, 0.f}, acc1 = {0.f, 0.f, 0.f, 0.f};
#pragma unroll
            for (int k0 = 0; k0 < H_; k0 += 64) {
                short8 a0 = *(const short8*)(aBase + (((k0 + kg * 8) * 2) ^ hswz));
                short8 b0 = *(const short8*)(whB + k0);
                acc0 = __builtin_amdgcn_mfma_f32_16x16x32_bf16(a0, b0, acc0, 0, 0, 0);
                short8 a1 = *(const short8*)(aBase + (((k0 + 32 + kg * 8) * 2) ^ hswz));
                short8 b1 = *(const short8*)(whB + k0 + 32);
                acc1 = __builtin_amdgcn_mfma_f32_16x16x32_bf16(a1, b1, acc1, 0, 0, 0);
            }
            const float* xB = x + ((size_t)arowg * S_ + s) * I_ + kg * 8;
            const unsigned short* wiB = Winbf + (size_t)col * I_ + kg * 8;
#pragma unroll
            for (int k2 = 0; k2 < I_; k2 += 64) {
                float4 a0f = *(const float4*)(xB + k2);
                float4 a1f = *(const float4*)(xB + k2 + 4);
                short8 a = { f2bf(a0f.x), f2bf(a0f.y), f2bf(a0f.z), f2bf(a0f.w),
                             f2bf(a1f.x), f2bf(a1f.y), f2bf(a1f.z), f2bf(a1f.w) };
                short8 b = *(const short8*)(wiB + k2);
                acc0 = __builtin_amdgcn_mfma_f32_16x16x32_bf16(a, b, acc0, 0, 0, 0);
                float4 a2f = *(const float4*)(xB + k2 + 32);
                float4 a3f = *(const float4*)(xB + k2 + 36);
                short8 a2 = { f2bf(a2f.x), f2bf(a2f.y), f2bf(a2f.z), f2bf(a2f.w),
                              f2bf(a3f.x), f2bf(a3f.y), f2bf(a3f.z), f2bf(a3f.w) };
                short8 b2 = *(const short8*)(wiB + k2 + 32);
                acc1 = __builtin_amdgcn_mfma_f32_16x16x32_bf16(a2, b2, acc1, 0, 0, 0);
            }
            f32x4 acc = acc0 + acc1;
            const bool last = (s == S_ - 1);
            f32x4 hv;
#pragma unroll
            for (int r = 0; r < 4; ++r) {
                hv[r] = ftanh(acc[r] + binc);
                hreg[r] = hv[r];
            }
            if (last) {
#pragma unroll
                for (int r = 0; r < 4; ++r)
                    out[(size_t)(row0 + r) * H_ + col] = hv[r];
            } else {
                publish_barrier(hout, hv, ep); ++ep;
                const unsigned short* tmp = hin; hin = hout; hout = (unsigned short*)tmp;
            }
        }
    }
}

extern "C" void kernel_launch(void* const* d_in, const int* in_sizes, int n_in,
                              void* d_out, int out_size, void* d_ws, size_t ws_size,
                              hipStream_t stream) {
    const float* x     = (const float*)d_in[0];
    const float* t     = (const float*)d_in[1];
    const float* W_in  = (const float*)d_in[2];
    const float* b_in  = (const float*)d_in[3];
    const float* W_h   = (const float*)d_in[4];
    const float* b_h   = (const float*)d_in[5];
    const float* W_ode = (const float*)d_in[6];
    const float* b_ode = (const float*)d_in[7];

    unsigned short* h0    = (unsigned short*)d_ws;
    unsigned short* h1    = h0 + (size_t)B_ * H_;
    unsigned short* Whbf  = h1 + (size_t)B_ * H_;
    unsigned short* Winbf = Whbf + (size_t)H_ * H_;
    unsigned* cnts = (unsigned*)(Winbf + (size_t)H_ * I_);
    // layout (uints): [512]=global counter; [1024 + bi*32 + bj] = epoch flags
    // (one 128B line per group, 16 used)

    (void)hipMemsetAsync(cnts, 0, (1024 + NG * 32) * sizeof(unsigned), stream);

    odernn_persist<<<dim3(NB), dim3(256), 0, stream>>>(
        x, t, W_in, b_in, W_h, b_h, W_ode, b_ode,
        (float*)d_out, h0, h1, Whbf, Winbf, cnts);
}

// Round 15
// 1264.731 us; speedup vs baseline: 1.2842x; 1.0146x over previous
//
#include <hip/hip_runtime.h>

#define B_ 256
#define S_ 64
#define I_ 256
#define H_ 1024
#define NODE_ 4
#define NB 256
#define NG 16    // row groups (16 batch rows each) -- data-decoupled
#define GSZ 16   // blocks per group (one 64-col strip each)

typedef __attribute__((ext_vector_type(8))) short short8;
typedef __attribute__((ext_vector_type(4))) float f32x4;

// fp32 -> bf16 round-to-nearest-even on raw bits
__device__ __forceinline__ short f2bf(float f) {
    unsigned u = __float_as_uint(f);
    u += 0x7fffu + ((u >> 16) & 1u);
    return (short)(u >> 16);
}
__device__ __forceinline__ unsigned pack2(float a, float b) {
    return (unsigned)(unsigned short)f2bf(a) | ((unsigned)(unsigned short)f2bf(b) << 16);
}

// fast tanh: |err| ~1e-7 rel, negligible vs bf16 h quantization
__device__ __forceinline__ float ftanh(float x) {
    float e = __expf(2.0f * fabsf(x));
    float r = __builtin_fmaf(-2.0f, __builtin_amdgcn_rcpf(e + 1.0f), 1.0f);
    return copysignf(r, x);
}

// Verified round-6 barrier: agent-scope counter at LLC (used once, startup).
__device__ __forceinline__ void gbar_slow(unsigned* cnt, unsigned target) {
    __syncthreads();
    if (threadIdx.x == 0) {
        __hip_atomic_fetch_add(cnt, 1u, __ATOMIC_RELAXED, __HIP_MEMORY_SCOPE_AGENT);
        while (__hip_atomic_load(cnt, __ATOMIC_RELAXED, __HIP_MEMORY_SCOPE_AGENT) < target)
            __builtin_amdgcn_s_sleep(1);
    }
    __syncthreads();
}

__global__ __launch_bounds__(256, 1)
void odernn_persist(const float* __restrict__ x, const float* __restrict__ t,
                    const float* __restrict__ W_in, const float* __restrict__ b_in,
                    const float* __restrict__ W_h, const float* __restrict__ b_h,
                    const float* __restrict__ W_ode, const float* __restrict__ b_ode,
                    float* __restrict__ out,
                    unsigned short* __restrict__ h0buf, unsigned short* __restrict__ h1buf,
                    unsigned short* __restrict__ Whbf, unsigned short* __restrict__ Winbf,
                    unsigned* __restrict__ cnts)
{
    __shared__ short Wlds[64 * 1024];   // 128 KB: bf16 W_ode 64-col slice, XOR-swizzled
    __shared__ short Hlds[16 * 1024];   //  32 KB: staged 16-row h strip, XOR-swizzled

    const int tid = threadIdx.x;
    const int blk = blockIdx.x;
    const int bi = blk & 15;          // row group (16 batch rows)
    const int bj = blk >> 4;          // 0..15 col strip (64 cols)
    const int lane = tid & 63;
    const int wv = tid >> 6;          // wave 0..3: owns cols wv*16..+16 of the strip
    const int r16 = lane & 15, kg = lane >> 4;

    // ---- prologue A: convert W_h, W_in to bf16 in ws (disjoint chunks) ----
    {
        const int g = blk * 256 + tid;              // 0..65535
        const float* src = W_h + (size_t)g * 16;    // 16 floats each
        unsigned* dst = (unsigned*)Whbf + (size_t)g * 8;
#pragma unroll
        for (int i = 0; i < 4; ++i) {
            float4 v = *(const float4*)(src + i * 4);
            __hip_atomic_store(dst + i * 2,     pack2(v.x, v.y), __ATOMIC_RELAXED, __HIP_MEMORY_SCOPE_AGENT);
            __hip_atomic_store(dst + i * 2 + 1, pack2(v.z, v.w), __ATOMIC_RELAXED, __HIP_MEMORY_SCOPE_AGENT);
        }
        float4 v = *(const float4*)(W_in + (size_t)g * 4);
        unsigned* d2 = (unsigned*)Winbf + (size_t)g * 2;
        __hip_atomic_store(d2,     pack2(v.x, v.y), __ATOMIC_RELAXED, __HIP_MEMORY_SCOPE_AGENT);
        __hip_atomic_store(d2 + 1, pack2(v.z, v.w), __ATOMIC_RELAXED, __HIP_MEMORY_SCOPE_AGENT);
    }

    // ---- prologue B: stage W_ode[bj*64 .. +64][:] as bf16 into LDS ----
    {
        const int c = tid >> 2;              // 0..63 slice row
        const int ks = (tid & 3) * 256;      // 256-float k segment
        const float* wsrc = W_ode + (size_t)(bj * 64 + c) * H_ + ks;
        for (int i = 0; i < 32; ++i) {
            float4 v0 = *(const float4*)(wsrc + i * 8);
            float4 v1 = *(const float4*)(wsrc + i * 8 + 4);
            short8 sv = { f2bf(v0.x), f2bf(v0.y), f2bf(v0.z), f2bf(v0.w),
                          f2bf(v1.x), f2bf(v1.y), f2bf(v1.z), f2bf(v1.w) };
            int idx = c * 1024 + ks + i * 8;
            *(short8*)&Wlds[idx ^ ((c & 7) << 3)] = sv;
        }
    }

    const int row0  = bi * 16 + kg * 4;            // first of 4 output rows (global)
    const int arowg = bi * 16 + r16;               // x row for the A fragment (global)
    const int col   = bj * 64 + wv * 16 + r16;     // output column (global)
    const int wbrow = wv * 16 + r16;               // Wlds row for B fragment

    const char* aBase = (const char*)Hlds + r16 * 2048;
    const int hswz = (r16 & 7) << 4;               // byte XOR for Hlds reads

    const float bodec = b_ode[col];
    const float binc  = b_in[col] + b_h[col];

    f32x4 hreg = {0.f, 0.f, 0.f, 0.f};
    // publish h0 = 0 (agent -> LLC, own tile)
#pragma unroll
    for (int r = 0; r < 4; ++r)
        __hip_atomic_store(&h0buf[(size_t)(row0 + r) * H_ + col], (unsigned short)0,
                           __ATOMIC_RELAXED, __HIP_MEMORY_SCOPE_AGENT);

    // one GLOBAL barrier (verified): conversions + h0 zeros visible everywhere
    gbar_slow(&cnts[512], NB);

    unsigned* flags = cnts + 1024 + bi * 32;   // 16 flag words (own 128B line per group)
    unsigned ep = 0;                           // publishes completed so far

    const int srow = tid >> 4, scl = tid & 15;
    const int swz_w = (srow & 7) << 4;

    // Gated incremental stage == group barrier + stage merged. For p=0..15:
    // poll the flag line (one wave-coalesced agent load + ballot) until
    // producer p has published epoch >= ep, then issue chunk-p load (1 u64 per
    // thread, 2KB per chunk). Early chunks' loads fly while late producers are
    // polled -> skew absorbed. Loads ordered after their flag by data dep
    // (ballot consumes the value); asm barrier pins compiler order.
    auto stage_gated = [&](const unsigned short* hsrc, unsigned epoch) {
        const unsigned long long* base =
            (const unsigned long long*)(hsrc + (size_t)bi * 16 * H_) + srow * 256 + scl;
        unsigned long long v[16];
        unsigned ready = 0;
#pragma unroll
        for (int p = 0; p < 16; ++p) {
            while (!(ready & (1u << p))) {
                unsigned fv = __hip_atomic_load(&flags[lane & 15],
                                                __ATOMIC_RELAXED, __HIP_MEMORY_SCOPE_AGENT);
                unsigned long long b = __ballot((int)(fv >= epoch));
                ready = (unsigned)(b & 0xFFFFu);
                if (!(ready & (1u << p))) __builtin_amdgcn_s_sleep(1);
            }
            asm volatile("" ::: "memory");
            v[p] = __hip_atomic_load(base + p * 16, __ATOMIC_RELAXED, __HIP_MEMORY_SCOPE_AGENT);
        }
#pragma unroll
        for (int p = 0; p < 16; ++p) {
            int byte = ((p * 16 + scl) * 8) ^ swz_w;
            *(unsigned long long*)((char*)Hlds + srow * 2048 + byte) = v[p];
        }
        __syncthreads();
    };

    // Publish own tile + arrive: stores -> block-wide drain -> flag = newep.
    // No trailing sync: the next stage_gated polls flags itself.
    auto publish = [&](unsigned short* dst, f32x4 pv, unsigned newep) {
#pragma unroll
        for (int r = 0; r < 4; ++r)
            __hip_atomic_store(&dst[(size_t)(row0 + r) * H_ + col],
                               (unsigned short)f2bf(pv[r]),
                               __ATOMIC_RELAXED, __HIP_MEMORY_SCOPE_AGENT);
        __syncthreads();   // every wave drains vmcnt before s_barrier -> stores at LLC
        if (tid == 0)
            __hip_atomic_store(&flags[bj], newep, __ATOMIC_RELAXED, __HIP_MEMORY_SCOPE_AGENT);
    };

    const unsigned short* hin = h0buf;
    unsigned short* hout = h1buf;

    for (int s = 0; s < S_; ++s) {
        if (s > 0) {
            const float dth = (t[s] - t[s - 1]) * 0.25f;
            for (int e = 0; e < NODE_; ++e) {
                stage_gated(hin, ep);
                f32x4 acc0 = {0.f, 0.f, 0.f, 0.f}, acc1 = {0.f, 0.f, 0.f, 0.f};
#pragma unroll
                for (int k0 = 0; k0 < H_; k0 += 64) {
                    short8 a0 = *(const short8*)(aBase + (((k0 + kg * 8) * 2) ^ hswz));
                    short8 b0 = *(const short8*)&Wlds[(wbrow * 1024 + k0 + kg * 8) ^ ((wbrow & 7) << 3)];
                    acc0 = __builtin_amdgcn_mfma_f32_16x16x32_bf16(a0, b0, acc0, 0, 0, 0);
                    short8 a1 = *(const short8*)(aBase + (((k0 + 32 + kg * 8) * 2) ^ hswz));
                    short8 b1 = *(const short8*)&Wlds[(wbrow * 1024 + k0 + 32 + kg * 8) ^ ((wbrow & 7) << 3)];
                    acc1 = __builtin_amdgcn_mfma_f32_16x16x32_bf16(a1, b1, acc1, 0, 0, 0);
                }
                f32x4 acc = acc0 + acc1;
#pragma unroll
                for (int r = 0; r < 4; ++r)
                    hreg[r] += dth * ftanh(acc[r] + bodec);
                publish(hout, hreg, ep + 1); ++ep;
                const unsigned short* tmp = hin; hin = hout; hout = (unsigned short*)tmp;
            }
        }
        // ---- update: h = tanh(x_s @ W_in^T + h @ W_h^T + b_in + b_h) ----
        {
            stage_gated(hin, ep);
            const unsigned short* whB = Whbf + (size_t)col * H_ + kg * 8;
            f32x4 acc0 = {0.f, 0.f, 0.f, 0.f}, acc1 = {0.f, 0.f, 0.f, 0.f};
#pragma unroll
            for (int k0 = 0; k0 < H_; k0 += 64) {
                short8 a0 = *(const short8*)(aBase + (((k0 + kg * 8) * 2) ^ hswz));
                short8 b0 = *(const short8*)(whB + k0);
                acc0 = __builtin_amdgcn_mfma_f32_16x16x32_bf16(a0, b0, acc0, 0, 0, 0);
                short8 a1 = *(const short8*)(aBase + (((k0 + 32 + kg * 8) * 2) ^ hswz));
                short8 b1 = *(const short8*)(whB + k0 + 32);
                acc1 = __builtin_amdgcn_mfma_f32_16x16x32_bf16(a1, b1, acc1, 0, 0, 0);
            }
            const float* xB = x + ((size_t)arowg * S_ + s) * I_ + kg * 8;
            const unsigned short* wiB = Winbf + (size_t)col * I_ + kg * 8;
#pragma unroll
            for (int k2 = 0; k2 < I_; k2 += 64) {
                float4 a0f = *(const float4*)(xB + k2);
                float4 a1f = *(const float4*)(xB + k2 + 4);
                short8 a = { f2bf(a0f.x), f2bf(a0f.y), f2bf(a0f.z), f2bf(a0f.w),
                             f2bf(a1f.x), f2bf(a1f.y), f2bf(a1f.z), f2bf(a1f.w) };
                short8 b = *(const short8*)(wiB + k2);
                acc0 = __builtin_amdgcn_mfma_f32_16x16x32_bf16(a, b, acc0, 0, 0, 0);
                float4 a2f = *(const float4*)(xB + k2 + 32);
                float4 a3f = *(const float4*)(xB + k2 + 36);
                short8 a2 = { f2bf(a2f.x), f2bf(a2f.y), f2bf(a2f.z), f2bf(a2f.w),
                              f2bf(a3f.x), f2bf(a3f.y), f2bf(a3f.z), f2bf(a3f.w) };
                short8 b2 = *(const short8*)(wiB + k2 + 32);
                acc1 = __builtin_amdgcn_mfma_f32_16x16x32_bf16(a2, b2, acc1, 0, 0, 0);
            }
            f32x4 acc = acc0 + acc1;
            const bool last = (s == S_ - 1);
            f32x4 hv;
#pragma unroll
            for (int r = 0; r < 4; ++r) {
                hv[r] = ftanh(acc[r] + binc);
                hreg[r] = hv[r];
            }
            if (last) {
#pragma unroll
                for (int r = 0; r < 4; ++r)
                    out[(size_t)(row0 + r) * H_ + col] = hv[r];
            } else {
                publish(hout, hv, ep + 1); ++ep;
                const unsigned short* tmp = hin; hin = hout; hout = (unsigned short*)tmp;
            }
        }
    }
}

extern "C" void kernel_launch(void* const* d_in, const int* in_sizes, int n_in,
                              void* d_out, int out_size, void* d_ws, size_t ws_size,
                              hipStream_t stream) {
    const float* x     = (const float*)d_in[0];
    const float* t     = (const float*)d_in[1];
    const float* W_in  = (const float*)d_in[2];
    const float* b_in  = (const float*)d_in[3];
    const float* W_h   = (const float*)d_in[4];
    const float* b_h   = (const float*)d_in[5];
    const float* W_ode = (const float*)d_in[6];
    const float* b_ode = (const float*)d_in[7];

    unsigned short* h0    = (unsigned short*)d_ws;
    unsigned short* h1    = h0 + (size_t)B_ * H_;
    unsigned short* Whbf  = h1 + (size_t)B_ * H_;
    unsigned short* Winbf = Whbf + (size_t)H_ * H_;
    unsigned* cnts = (unsigned*)(Winbf + (size_t)H_ * I_);
    // layout (uints): [512]=global counter; [1024 + bi*32 + bj] = epoch flags
    // (one 128B line per group, 16 used)

    (void)hipMemsetAsync(cnts, 0, (1024 + NG * 32) * sizeof(unsigned), stream);

    odernn_persist<<<dim3(NB), dim3(256), 0, stream>>>(
        x, t, W_in, b_in, W_h, b_h, W_ode, b_ode,
        (float*)d_out, h0, h1, Whbf, Winbf, cnts);
}